// Round 14
// baseline (236.646 us; speedup 1.0000x reference)
//
#include <hip/hip_runtime.h>
#include <math.h>

#define EPS  1e-5f
#define EPS2 1e-10f
#define MAXN (1.0f - EPS)

using short8  = __attribute__((ext_vector_type(8))) short;
using floatx4 = __attribute__((ext_vector_type(4))) float;
using float2v = __attribute__((ext_vector_type(2))) float;

// DPP cross-lane: pure VALU, never touches the LDS pipe
template <int CTRL>
static __device__ __forceinline__ float qperm(float x) {
  return __int_as_float(__builtin_amdgcn_update_dpp(
      __float_as_int(x), __float_as_int(x), CTRL, 0xF, 0xF, false));
}
#define QP_XOR1    0xB1   // quad_perm [1,0,3,2]
#define QP_XOR2    0x4E   // quad_perm [2,3,0,1]
#define QP_HALFMIR 0x141  // row_half_mirror: lane -> lane^7 within 8

#if __has_builtin(__builtin_elementwise_fma)
static __device__ __forceinline__ float2v fma2(float2v a, float2v b, float2v c) {
  return __builtin_elementwise_fma(a, b, c);
}
#else
static __device__ __forceinline__ float2v fma2(float2v a, float2v b, float2v c) {
  float2v r; r.x = fmaf(a.x, b.x, c.x); r.y = fmaf(a.y, b.y, c.y); return r;
}
#endif

// truncation bf16 split, pair-packed: low short = element a, high short = element b
static __device__ __forceinline__ int pack_hi2(float a, float b) {
  return (int)((__float_as_uint(a) >> 16) | (__float_as_uint(b) & 0xFFFF0000u));
}
static __device__ __forceinline__ float hi_of(float a) {
  return __uint_as_float(__float_as_uint(a) & 0xFFFF0000u);
}

static __device__ __forceinline__ float logmap_f(float ss) {
  const float r = sqrtf(fmaxf(ss, EPS2));
  float at;
  if (r >= MAXN) {
    at = 0.5f * logf((r * (2.0f - EPS) + EPS) / (EPS * (1.0f + r)));
  } else {
    at = 0.5f * logf((1.0f + r) / (1.0f - r));
  }
  return (1.0f + EPS) * at / r;
}

// ---------- K0: split fp32 rows into bf16 hi/lo (+ optional logmap f) ----------
// One wave per 512-elem row; 8 elems/lane.
__global__ __launch_bounds__(256) void k_split(const float* __restrict__ s0,
                                               const float* __restrict__ s1,
                                               const float* __restrict__ s2,
                                               const float* __restrict__ s3,
                                               short* __restrict__ hi,
                                               short* __restrict__ lo,
                                               float* __restrict__ f, int rows_per) {
  const int z = blockIdx.y, t = threadIdx.x;
  const int wv = t >> 6, lane = t & 63;
  const int row = blockIdx.x * 4 + wv;
  const float* src = (z == 0) ? s0 : ((z == 1) ? s1 : ((z == 2) ? s2 : s3));
  const float* rp = src + (size_t)row * 512 + lane * 8;
  const float4 a = *(const float4*)&rp[0];
  const float4 b = *(const float4*)&rp[4];
  const float v[8] = {a.x, a.y, a.z, a.w, b.x, b.y, b.z, b.w};
  int h4[4], l4[4];
#pragma unroll
  for (int i = 0; i < 4; ++i) {
    h4[i] = pack_hi2(v[2 * i], v[2 * i + 1]);
    l4[i] = pack_hi2(v[2 * i] - hi_of(v[2 * i]), v[2 * i + 1] - hi_of(v[2 * i + 1]));
  }
  const size_t off = ((size_t)z * rows_per + row) * 512 + lane * 8;
  *(int4*)&hi[off] = *(int4*)h4;
  *(int4*)&lo[off] = *(int4*)l4;
  if (f) {
    float ssq = 0.f;
#pragma unroll
    for (int e = 0; e < 8; ++e) ssq = fmaf(v[e], v[e], ssq);
#pragma unroll
    for (int m = 32; m; m >>= 1) ssq += __shfl_xor(ssq, m, 64);
    if (lane == 0) f[z * rows_per + row] = logmap_f(ssq);
  }
}

// ---------- K2: C = f[row]*(A @ W^T), inputs PRE-SPLIT bf16 hi/lo ----------
__global__ __launch_bounds__(256) void k_gemm_pre(
    const short* __restrict__ Ahi, const short* __restrict__ Alo,
    const short* __restrict__ Whi, const short* __restrict__ Wlo,
    const float* __restrict__ f, float* __restrict__ Cbase) {
  const int z = blockIdx.z;
  const short* Ah_ = Ahi + (size_t)z * (2048 * 512);
  const short* Al_ = Alo + (size_t)z * (2048 * 512);
  const short* Wh_ = Whi + (size_t)z * (512 * 512);
  const short* Wl_ = Wlo + (size_t)z * (512 * 512);
  const float* fz = f + z * 2048;
  float* C = Cbase + (size_t)z * (2048 * 512);
  __shared__ short Ah[64][72], Al[64][72], Wh[64][72], Wl[64][72];
  const int t = threadIdx.x;
  const int n0 = blockIdx.x * 64;
  const int m0 = blockIdx.y * 64;
  const int row = t >> 2, c0 = (t & 3) * 16;
  const int w = t >> 6, lane = t & 63;
  const int quad = lane >> 4, l16 = lane & 15;
  const int mw = (w & 1) * 32, nw = (w >> 1) * 32;
  floatx4 acc[2][2];
#pragma unroll
  for (int i = 0; i < 2; ++i)
#pragma unroll
    for (int j = 0; j < 2; ++j) acc[i][j] = (floatx4){0.f, 0.f, 0.f, 0.f};

  for (int k0 = 0; k0 < 512; k0 += 64) {
    const short8 a0 = *(const short8*)&Ah_[(size_t)(n0 + row) * 512 + k0 + c0];
    const short8 a1 = *(const short8*)&Ah_[(size_t)(n0 + row) * 512 + k0 + c0 + 8];
    const short8 b0 = *(const short8*)&Al_[(size_t)(n0 + row) * 512 + k0 + c0];
    const short8 b1 = *(const short8*)&Al_[(size_t)(n0 + row) * 512 + k0 + c0 + 8];
    const short8 c0v = *(const short8*)&Wh_[(size_t)(m0 + row) * 512 + k0 + c0];
    const short8 c1v = *(const short8*)&Wh_[(size_t)(m0 + row) * 512 + k0 + c0 + 8];
    const short8 d0v = *(const short8*)&Wl_[(size_t)(m0 + row) * 512 + k0 + c0];
    const short8 d1v = *(const short8*)&Wl_[(size_t)(m0 + row) * 512 + k0 + c0 + 8];
    __syncthreads();
    *(short8*)&Ah[row][c0] = a0; *(short8*)&Ah[row][c0 + 8] = a1;
    *(short8*)&Al[row][c0] = b0; *(short8*)&Al[row][c0 + 8] = b1;
    *(short8*)&Wh[row][c0] = c0v; *(short8*)&Wh[row][c0 + 8] = c1v;
    *(short8*)&Wl[row][c0] = d0v; *(short8*)&Wl[row][c0 + 8] = d1v;
    __syncthreads();
#pragma unroll
    for (int kk = 0; kk < 64; kk += 32) {
      short8 ah[2], al[2], bh[2], bl[2];
#pragma unroll
      for (int i = 0; i < 2; ++i) {
        ah[i] = *(const short8*)&Ah[mw + i * 16 + l16][kk + quad * 8];
        al[i] = *(const short8*)&Al[mw + i * 16 + l16][kk + quad * 8];
        bh[i] = *(const short8*)&Wh[nw + i * 16 + l16][kk + quad * 8];
        bl[i] = *(const short8*)&Wl[nw + i * 16 + l16][kk + quad * 8];
      }
#pragma unroll
      for (int i = 0; i < 2; ++i)
#pragma unroll
        for (int j = 0; j < 2; ++j) {
          acc[i][j] = __builtin_amdgcn_mfma_f32_16x16x32_bf16(ah[i], bh[j], acc[i][j], 0, 0, 0);
          acc[i][j] = __builtin_amdgcn_mfma_f32_16x16x32_bf16(ah[i], bl[j], acc[i][j], 0, 0, 0);
          acc[i][j] = __builtin_amdgcn_mfma_f32_16x16x32_bf16(al[i], bh[j], acc[i][j], 0, 0, 0);
        }
    }
  }
#pragma unroll
  for (int i = 0; i < 2; ++i) {
    const int lrow_base = mw + i * 16 + quad * 4;
#pragma unroll
    for (int r = 0; r < 4; ++r) {
      const float fv = fz[n0 + lrow_base + r];
#pragma unroll
      for (int j = 0; j < 2; ++j)
        C[(size_t)(n0 + lrow_base + r) * 512 + m0 + nw + j * 16 + l16] = fv * acc[i][j][r];
    }
  }
}

// ---------- K3: expmap0 + mobius bias; Q/K emitted PRE-SPLIT bf16; V fp32 ----------
__global__ __launch_bounds__(256) void k_post(const float* __restrict__ tin,
                                              const float* __restrict__ b0,
                                              const float* __restrict__ b1,
                                              const float* __restrict__ b2,
                                              short* __restrict__ Qhi, short* __restrict__ Qlo,
                                              short* __restrict__ Khi, short* __restrict__ Klo,
                                              float* __restrict__ Vb, float* __restrict__ ofin,
                                              float* __restrict__ qn, float* __restrict__ kn,
                                              float* __restrict__ vn,
                                              float* __restrict__ rowsum_init, int final_mode) {
  const int t = threadIdx.x;
  const int wv = t >> 6, lane = t & 63;
  const int nrow = blockIdx.x * 4 + wv;
  const int z = blockIdx.y;
  const float* tv = tin + ((size_t)z * 2048 + nrow) * 512;
  const float* bias = (z == 0) ? b0 : ((z == 1) ? b1 : b2);
  const int e0 = lane * 8;
  const float4 tp0 = *(const float4*)&tv[e0];
  const float4 tp1 = *(const float4*)&tv[e0 + 4];
  const float4 bp0 = *(const float4*)&bias[e0];
  const float4 bp1 = *(const float4*)&bias[e0 + 4];
  const float tpv[8] = {tp0.x, tp0.y, tp0.z, tp0.w, tp1.x, tp1.y, tp1.z, tp1.w};
  const float bpv[8] = {bp0.x, bp0.y, bp0.z, bp0.w, bp1.x, bp1.y, bp1.z, bp1.w};
  float p_tt = 0.f, p_tb = 0.f, p_bb = 0.f;
#pragma unroll
  for (int e = 0; e < 8; ++e) {
    p_tt = fmaf(tpv[e], tpv[e], p_tt);
    p_tb = fmaf(tpv[e], bpv[e], p_tb);
    p_bb = fmaf(bpv[e], bpv[e], p_bb);
  }
#pragma unroll
  for (int m = 32; m; m >>= 1) {
    p_tt += __shfl_xor(p_tt, m, 64);
    p_tb += __shfl_xor(p_tb, m, 64);
    p_bb += __shfl_xor(p_bb, m, 64);
  }
  const float s_tt = p_tt, s_tb = p_tb, s_bb = p_bb;
  const float tn = sqrtf(fmaxf(s_tt, EPS2));
  const float th = tanhf(tn / (1.0f + EPS));
  const float g = th / tn;
  const float rnorm = th * (sqrtf(s_tt) / tn);
  const float sr = (rnorm >= MAXN) ? (MAXN / (rnorm + EPS)) : 1.0f;
  const float gr = g * sr;
  const float rn = (rnorm * sr) * (rnorm * sr);
  const float bnorm = sqrtf(fmaxf(s_bb, EPS2));
  const float sb = (bnorm >= MAXN) ? (MAXN / (bnorm + EPS)) : 1.0f;
  const float xy = gr * sb * s_tb;
  const float yn = (sb * sb) * s_bb;
  const float Af = 1.0f + 2.0f * xy + yn;
  const float Cf = 1.0f - rn;
  const float den = 1.0f + 2.0f * xy + rn * yn + EPS;
  const float id = 1.0f / den;
  const float on_raw = (Af * Af * rn + 2.0f * Af * Cf * xy + Cf * Cf * yn) * (id * id);
  const float no = sqrtf(fmaxf(on_raw, EPS2));
  const float so = (no >= MAXN) ? (MAXN / (no + EPS)) : 1.0f;
  const float ms = id * so;
  const float ca = gr * Af * ms;
  const float cb = sb * Cf * ms;
  float v[8];
#pragma unroll
  for (int e = 0; e < 8; ++e) v[e] = ca * tpv[e] + cb * bpv[e];
  if (final_mode) {
    float4 oa; oa.x = v[0]; oa.y = v[1]; oa.z = v[2]; oa.w = v[3];
    float4 ob; ob.x = v[4]; ob.y = v[5]; ob.z = v[6]; ob.w = v[7];
    *(float4*)&ofin[(size_t)nrow * 512 + e0] = oa;
    *(float4*)&ofin[(size_t)nrow * 512 + e0 + 4] = ob;
    return;
  }
  float hp = 0.f;
#pragma unroll
  for (int e = 0; e < 8; ++e) hp = fmaf(v[e], v[e], hp);
  hp += __shfl_xor(hp, 1, 64);
  hp += __shfl_xor(hp, 2, 64);
  hp += __shfl_xor(hp, 4, 64);
  const float hnr = sqrtf(fmaxf(hp, EPS2));
  float sh = 1.0f;
  if (z != 2) sh = (hnr >= MAXN) ? (MAXN / (hnr + EPS)) : 1.0f;
  const int b = nrow >> 9, s = nrow & 511, h = lane >> 3, d = (lane & 7) * 8;
  const size_t off = (((size_t)(b * 8 + h) * 512 + s) * 64 + d);
  float vv[8];
#pragma unroll
  for (int e = 0; e < 8; ++e) vv[e] = v[e] * sh;
  if (z == 2) {
    float4 oa; oa.x = vv[0]; oa.y = vv[1]; oa.z = vv[2]; oa.w = vv[3];
    float4 ob; ob.x = vv[4]; ob.y = vv[5]; ob.z = vv[6]; ob.w = vv[7];
    *(float4*)&Vb[off] = oa;
    *(float4*)&Vb[off + 4] = ob;
    if ((lane & 7) == 0) vn[(size_t)(b * 8 + h) * 512 + s] = hp;
  } else {
    short* hz = (z == 0) ? Qhi : Khi;
    short* lz = (z == 0) ? Qlo : Klo;
    int h4[4], l4[4];
#pragma unroll
    for (int i = 0; i < 4; ++i) {
      h4[i] = pack_hi2(vv[2 * i], vv[2 * i + 1]);
      l4[i] = pack_hi2(vv[2 * i] - hi_of(vv[2 * i]), vv[2 * i + 1] - hi_of(vv[2 * i + 1]));
    }
    *(int4*)&hz[off] = *(int4*)h4;
    *(int4*)&lz[off] = *(int4*)l4;
    float* nz = (z == 0) ? qn : kn;
    if ((lane & 7) == 0) nz[(size_t)(b * 8 + h) * 512 + s] = hp * sh * sh;
  }
  if (z == 0 && lane < 8) rowsum_init[((size_t)b * 8 + lane) * 512 + s] = 0.0f;
}

// ---------- K4: QK^T via PRE-SPLIT bf16 MFMA; r = exp(-dist) exactly ----------
__global__ __launch_bounds__(256) void k_logits(const short* __restrict__ Qhi,
                                                const short* __restrict__ Qlo,
                                                const short* __restrict__ Khi,
                                                const short* __restrict__ Klo,
                                                const float* __restrict__ qn,
                                                const float* __restrict__ kn,
                                                float* __restrict__ attn,
                                                float* __restrict__ rowsum) {
  const int bh = blockIdx.z;
  const int i0 = blockIdx.x * 64;
  const int j0 = blockIdx.y * 64;
  const short* Qh_ = Qhi + (size_t)bh * 512 * 64;
  const short* Ql_ = Qlo + (size_t)bh * 512 * 64;
  const short* Kh_ = Khi + (size_t)bh * 512 * 64;
  const short* Kl_ = Klo + (size_t)bh * 512 * 64;
  __shared__ short Qh[64][72], Ql[64][72], Kh[64][72], Kl[64][72];
  const int t = threadIdx.x;
  const int row = t >> 2, c0 = (t & 3) * 16;
  const int w = t >> 6, lane = t & 63;
  const int quad = lane >> 4, l16 = lane & 15;
  const int mw = (w & 1) * 32, nw = (w >> 1) * 32;
  const short8 q0 = *(const short8*)&Qh_[(size_t)(i0 + row) * 64 + c0];
  const short8 q1 = *(const short8*)&Qh_[(size_t)(i0 + row) * 64 + c0 + 8];
  const short8 q2 = *(const short8*)&Ql_[(size_t)(i0 + row) * 64 + c0];
  const short8 q3 = *(const short8*)&Ql_[(size_t)(i0 + row) * 64 + c0 + 8];
  const short8 k0v = *(const short8*)&Kh_[(size_t)(j0 + row) * 64 + c0];
  const short8 k1v = *(const short8*)&Kh_[(size_t)(j0 + row) * 64 + c0 + 8];
  const short8 k2v = *(const short8*)&Kl_[(size_t)(j0 + row) * 64 + c0];
  const short8 k3v = *(const short8*)&Kl_[(size_t)(j0 + row) * 64 + c0 + 8];
  *(short8*)&Qh[row][c0] = q0; *(short8*)&Qh[row][c0 + 8] = q1;
  *(short8*)&Ql[row][c0] = q2; *(short8*)&Ql[row][c0 + 8] = q3;
  *(short8*)&Kh[row][c0] = k0v; *(short8*)&Kh[row][c0 + 8] = k1v;
  *(short8*)&Kl[row][c0] = k2v; *(short8*)&Kl[row][c0 + 8] = k3v;
  __syncthreads();
  floatx4 acc[2][2];
#pragma unroll
  for (int i = 0; i < 2; ++i)
#pragma unroll
    for (int j = 0; j < 2; ++j) acc[i][j] = (floatx4){0.f, 0.f, 0.f, 0.f};
#pragma unroll
  for (int kk = 0; kk < 64; kk += 32) {
    short8 ah[2], al[2], bhv[2], blv[2];
#pragma unroll
    for (int i = 0; i < 2; ++i) {
      ah[i]  = *(const short8*)&Qh[mw + i * 16 + l16][kk + quad * 8];
      al[i]  = *(const short8*)&Ql[mw + i * 16 + l16][kk + quad * 8];
      bhv[i] = *(const short8*)&Kh[nw + i * 16 + l16][kk + quad * 8];
      blv[i] = *(const short8*)&Kl[nw + i * 16 + l16][kk + quad * 8];
    }
#pragma unroll
    for (int i = 0; i < 2; ++i)
#pragma unroll
      for (int j = 0; j < 2; ++j) {
        acc[i][j] = __builtin_amdgcn_mfma_f32_16x16x32_bf16(ah[i], bhv[j], acc[i][j], 0, 0, 0);
        acc[i][j] = __builtin_amdgcn_mfma_f32_16x16x32_bf16(ah[i], blv[j], acc[i][j], 0, 0, 0);
        acc[i][j] = __builtin_amdgcn_mfma_f32_16x16x32_bf16(al[i], bhv[j], acc[i][j], 0, 0, 0);
      }
  }
#pragma unroll
  for (int i = 0; i < 2; ++i) {
    float rs_acc[4] = {0.f, 0.f, 0.f, 0.f};
#pragma unroll
    for (int r = 0; r < 4; ++r) {
      const int grow = i0 + mw + i * 16 + quad * 4 + r;
      const float qni = qn[(size_t)bh * 512 + grow];
      const float rq = 1.0f - qni;
#pragma unroll
      for (int j = 0; j < 2; ++j) {
        const int gcol = j0 + nw + j * 16 + l16;
        const float knj = kn[(size_t)bh * 512 + gcol];
        const float num = fmaxf(qni + knj - 2.0f * acc[i][j][r], 0.0f);
        const float den = fmaxf(rq * (1.0f - knj), EPS);
        const float wv = fmaf(2.0f * num, __builtin_amdgcn_rcpf(den), EPS);
        const float s_ = 1.0f + wv + sqrtf(wv * (wv + 2.0f));
        const float rr = __builtin_amdgcn_rcpf(s_);
        rs_acc[r] += rr;
        attn[((size_t)bh * 512 + grow) * 512 + gcol] = rr;
      }
    }
#pragma unroll
    for (int r = 0; r < 4; ++r) {
      float v = rs_acc[r];
      v += __shfl_xor(v, 1, 64); v += __shfl_xor(v, 2, 64);
      v += __shfl_xor(v, 4, 64); v += __shfl_xor(v, 8, 64);
      if (l16 == 0)
        atomicAdd(&rowsum[(size_t)bh * 512 + i0 + mw + i * 16 + quad * 4 + r], v);
    }
  }
}

// ---------- K6 v11: mobius scan, 8 lanes/row + one-step dot LOOKAHEAD ----------
__global__ __launch_bounds__(256) void k_scan(const float* __restrict__ V,
                                              const float* __restrict__ vn,
                                              const float* __restrict__ rw,
                                              const float* __restrict__ rowsum,
                                              float* __restrict__ att) {
  __shared__ __align__(16) float v_lds[64 * 64];
  __shared__ __align__(16) float swyn_lds[64 * 66];
  __shared__ float g_lds[64];
  const int blk = blockIdx.x;
  const int bh = blk >> 4;
  const int i0 = (blk & 15) * 32;
  const int t = threadIdx.x;
  const int lane = t & 63, w = t >> 6;
  const int row_blk = w * 8 + (lane >> 3);
  const int sub = lane & 7;
  const int d0 = sub * 8;
  const float* Vb = V + (size_t)bh * 512 * 64;
  const float* vnb = vn + (size_t)bh * 512;
  const float* arow = rw + ((size_t)bh * 512 + i0 + row_blk) * 512;
  const float inv_s = __builtin_amdgcn_rcpf(rowsum[(size_t)bh * 512 + i0 + row_blk]);

  float2v wsv[4];
#pragma unroll
  for (int k = 0; k < 4; ++k) wsv[k] = (float2v){0.f, 0.f};
  float xn = 0.0f;

  for (int jc = 0; jc < 512; jc += 64) {
#pragma unroll
    for (int it = 0; it < 4; ++it) {
      const int idx4 = it * 256 + t;
      *(float4*)&v_lds[idx4 * 4] = *(const float4*)&Vb[(size_t)jc * 64 + idx4 * 4];
    }
    const float4 a0 = *(const float4*)&arow[jc + sub * 8];
    const float4 a1 = *(const float4*)&arow[jc + sub * 8 + 4];
    const float4 n0 = *(const float4*)&vnb[jc + sub * 8];
    const float4 n1 = *(const float4*)&vnb[jc + sub * 8 + 4];
    const float wq[8] = {a0.x, a0.y, a0.z, a0.w, a1.x, a1.y, a1.z, a1.w};
    const float nq[8] = {n0.x, n0.y, n0.z, n0.w, n1.x, n1.y, n1.z, n1.w};
#pragma unroll
    for (int e = 0; e < 8; ++e) {
      const float wgt = wq[e] * inv_s;
      float2 p; p.x = wgt; p.y = (wgt * wgt) * nq[e];
      *(float2*)&swyn_lds[(sub * 8 + e) * 66 + row_blk * 2] = p;
    }
    __syncthreads();

    {
      const int jg = row_blk * 2;
      const float4 va0 = *(const float4*)&v_lds[jg * 64 + d0];
      const float4 va1 = *(const float4*)&v_lds[jg * 64 + d0 + 4];
      const float4 vb0 = *(const float4*)&v_lds[(jg + 1) * 64 + d0];
      const float4 vb1 = *(const float4*)&v_lds[(jg + 1) * 64 + d0 + 4];
      const float4 vc0 = *(const float4*)&v_lds[((jg + 2) & 63) * 64 + d0];
      const float4 vc1 = *(const float4*)&v_lds[((jg + 2) & 63) * 64 + d0 + 4];
      float p0 = va0.x * vb0.x + va0.y * vb0.y + va0.z * vb0.z + va0.w * vb0.w +
                 va1.x * vb1.x + va1.y * vb1.y + va1.z * vb1.z + va1.w * vb1.w;
      float p1 = vb0.x * vc0.x + vb0.y * vc0.y + vb0.z * vc0.z + vb0.w * vc0.w +
                 vb1.x * vc1.x + vb1.y * vc1.y + vb1.z * vc1.z + vb1.w * vc1.w;
      p0 += qperm<QP_XOR1>(p0); p0 += qperm<QP_XOR2>(p0); p0 += qperm<QP_HALFMIR>(p0);
      p1 += qperm<QP_XOR1>(p1); p1 += qperm<QP_XOR2>(p1); p1 += qperm<QP_HALFMIR>(p1);
      if (sub == 0) { g_lds[jg] = p0; g_lds[jg + 1] = p1; }
    }
    float2v vcur[4];
    {
      const float4 c0v = *(const float4*)&v_lds[d0];
      const float4 c1v = *(const float4*)&v_lds[d0 + 4];
      vcur[0] = (float2v){c0v.x, c0v.y}; vcur[1] = (float2v){c0v.z, c0v.w};
      vcur[2] = (float2v){c1v.x, c1v.y}; vcur[3] = (float2v){c1v.z, c1v.w};
    }
    float2v dd = wsv[0] * vcur[0];
    dd = fma2(wsv[1], vcur[1], dd);
    dd = fma2(wsv[2], vcur[2], dd);
    dd = fma2(wsv[3], vcur[3], dd);
    float D = dd.x + dd.y;
    D += qperm<QP_XOR1>(D); D += qperm<QP_XOR2>(D); D += qperm<QP_HALFMIR>(D);
    __syncthreads();

#pragma unroll
    for (int j = 0; j < 64; ++j) {
      const float2 sy2 = *(const float2*)&swyn_lds[j * 66 + row_blk * 2];
      const float sw = sy2.x, yn = sy2.y;
      const float xnyn1 = fmaf(xn, yn, 1.0f + EPS);
      const float sxy   = xn + yn;
      const float ynp1  = 1.0f + yn;
      const float Cfsw  = (1.0f - xn) * sw;
      float2v vnx[4];
      float E = 0.0f;
      if (j < 63) {
        const float4 nx0 = *(const float4*)&v_lds[(j + 1) * 64 + d0];
        const float4 nx1 = *(const float4*)&v_lds[(j + 1) * 64 + d0 + 4];
        vnx[0] = (float2v){nx0.x, nx0.y}; vnx[1] = (float2v){nx0.z, nx0.w};
        vnx[2] = (float2v){nx1.x, nx1.y}; vnx[3] = (float2v){nx1.z, nx1.w};
        float2v ee = wsv[0] * vnx[0];
        ee = fma2(wsv[1], vnx[1], ee);
        ee = fma2(wsv[2], vnx[2], ee);
        ee = fma2(wsv[3], vnx[3], ee);
        E = ee.x + ee.y;
        E += qperm<QP_XOR1>(E); E += qperm<QP_XOR2>(E); E += qperm<QP_HALFMIR>(E);
      }
      const float xy  = sw * D;
      const float den = fmaf(2.0f, xy, xnyn1);
      const float s2  = fmaf(2.0f, xy, sxy);
      const float Af  = fmaf(2.0f, xy, ynp1);
      const float id  = __builtin_amdgcn_rcpf(den);
      const float dn  = den - EPS;
      const float am  = Af * id;
      const float cm  = Cfsw * id;
      xn = (s2 * id) * (dn * id);
      const float2v amv = {am, am};
      const float2v cmv = {cm, cm};
      wsv[0] = fma2(amv, wsv[0], cmv * vcur[0]);
      wsv[1] = fma2(amv, wsv[1], cmv * vcur[1]);
      wsv[2] = fma2(amv, wsv[2], cmv * vcur[2]);
      wsv[3] = fma2(amv, wsv[3], cmv * vcur[3]);
      if (j < 63) {
        D = fmaf(am, E, cm * g_lds[j]);
        vcur[0] = vnx[0]; vcur[1] = vnx[1]; vcur[2] = vnx[2]; vcur[3] = vnx[3];
      }
    }
    __syncthreads();
  }
  const int b = bh >> 3, h = bh & 7;
  float* o = att + (((size_t)b * 512 + i0 + row_blk) * 512 + h * 64 + d0);
  float4 s0; s0.x = wsv[0].x; s0.y = wsv[0].y; s0.z = wsv[1].x; s0.w = wsv[1].y;
  float4 s1; s1.x = wsv[2].x; s1.y = wsv[2].y; s1.z = wsv[3].x; s1.w = wsv[3].y;
  *(float4*)&o[0] = s0;
  *(float4*)&o[4] = s1;
}

extern "C" void kernel_launch(void* const* d_in, const int* in_sizes, int n_in,
                              void* d_out, int out_size, void* d_ws, size_t ws_size,
                              hipStream_t stream) {
  const float* query = (const float*)d_in[0];
  const float* key_  = (const float*)d_in[1];
  const float* value = (const float*)d_in[2];
  const float* Wq = (const float*)d_in[3];
  const float* bq = (const float*)d_in[4];
  const float* Wk = (const float*)d_in[5];
  const float* bk = (const float*)d_in[6];
  const float* Wv = (const float*)d_in[7];
  const float* bv = (const float*)d_in[8];
  const float* Wo = (const float*)d_in[9];
  const float* bo = (const float*)d_in[10];
  float* ws = (float*)d_ws;
  const size_t M = 1u << 20;  // 1M floats
  // [0..2M): Q/K bf16 splits (each 1M shorts = 0.5M floats)
  short* Qhi = (short*)(ws);
  short* Qlo = (short*)(ws + (M >> 1));
  short* Khi = (short*)(ws + M);
  short* Klo = (short*)(ws + M + (M >> 1));
  float* Vb  = ws + 2 * M;                 // [2M..3M)
  float* qn  = ws + 3 * M;                 // small arrays in [3M..4M)
  float* kn  = qn + 16384;
  float* vn  = kn + 16384;
  float* rowsum = vn + 16384;
  float* f3  = rowsum + 16384;             // [3,2048]
  float* fo  = f3 + 3 * 2048;              // [2048]
  float* rw  = ws + 4 * M;                 // [4M..12M): 32 MB attn weights
  // input splits overlap rw (dead before logits writes rw)
  short* Ahi3 = (short*)(ws + 4 * M);      // 3M shorts
  short* Alo3 = (short*)(ws + 4 * M + M + (M >> 1));
  // att splits overlap rw (written after scan consumed rw)
  short* atthi = (short*)(ws + 4 * M);
  short* attlo = (short*)(ws + 4 * M + (M >> 1));
  float* t3  = ws + 12 * M;                // 3x [2048,512]
  float* att = ws + 15 * M;                // [2048,512]
  float* to_ = ws + 16 * M;                // [2048,512]
  short* Whi4 = (short*)(ws + 17 * M);     // 4x [512,512] bf16 hi
  short* Wlo4 = (short*)(ws + 17 * M + (M >> 1));

  // pre-split inputs (+f) and all four weight matrices
  k_split<<<dim3(512, 3), 256, 0, stream>>>(query, key_, value, nullptr, Ahi3, Alo3, f3, 2048);
  k_split<<<dim3(128, 4), 256, 0, stream>>>(Wq, Wk, Wv, Wo, Whi4, Wlo4, nullptr, 512);
  // QKV hyperbolic linears
  k_gemm_pre<<<dim3(32, 8, 3), 256, 0, stream>>>(Ahi3, Alo3, Whi4, Wlo4, f3, t3);
  k_post<<<dim3(512, 3), 256, 0, stream>>>(t3, bq, bk, bv, Qhi, Qlo, Khi, Klo, Vb,
                                           nullptr, qn, kn, vn, rowsum, 0);
  // distance weights + rowsums
  k_logits<<<dim3(8, 8, 32), 256, 0, stream>>>(Qhi, Qlo, Khi, Klo, qn, kn, rw, rowsum);
  // sequential mobius aggregation
  k_scan<<<512, 256, 0, stream>>>(Vb, vn, rw, rowsum, att);
  // output hyperbolic linear
  k_split<<<dim3(512, 1), 256, 0, stream>>>(att, att, att, att, atthi, attlo, fo, 2048);
  k_gemm_pre<<<dim3(32, 8, 1), 256, 0, stream>>>(atthi, attlo, Whi4 + 3 * 512 * 512,
                                                 Wlo4 + 3 * 512 * 512, fo, to_);
  k_post<<<dim3(512, 1), 256, 0, stream>>>(to_, bo, bo, bo, nullptr, nullptr, nullptr,
                                           nullptr, nullptr, (float*)d_out,
                                           nullptr, nullptr, nullptr, nullptr, 1);
}